// Round 1
// baseline (527.282 us; speedup 1.0000x reference)
//
#include <hip/hip_runtime.h>
#include <stdint.h>

#define A_N 65536
#define B_N 16
#define G_N 64
#define FEPS 1e-7f

// ---------------- K0: init workspace (ws is poisoned 0xAA before every call) ----------------
__global__ void dl_init(unsigned long long* __restrict__ gt_key, float* __restrict__ acc) {
  int t = blockIdx.x * blockDim.x + threadIdx.x;
  if (t < B_N * G_N) gt_key[t] = 0xFFFFFFFFull;  // key(iou=0, anchor 0): matches numpy argmax of all-zero column
  if (t < 64) acc[t] = 0.0f;                     // [0:16) loc, [16:32) pos_sum, [32:48) npos, [48:64) conf
}

// ---------------- K1: per-anchor best gt (max+argmax), per-gt best anchor (argmax) ----------------
__global__ __launch_bounds__(256) void dl_pass1(
    const float4* __restrict__ bbox, const float4* __restrict__ gt,
    float* __restrict__ best_iou, uint32_t* __restrict__ best_idx,
    unsigned long long* __restrict__ gt_key) {
  const int img = blockIdx.y;
  const int a = blockIdx.x * 256 + threadIdx.x;
  const int t = threadIdx.x;

  __shared__ float4 sg[G_N];
  __shared__ float sga[G_N];
  __shared__ unsigned long long smax[G_N];

  if (t < G_N) {
    float4 q = gt[img * G_N + t];
    sg[t] = q;
    // exact f32, no contraction (matches numpy bit-for-bit)
    sga[t] = __fmul_rn(__fsub_rn(q.z, q.x), __fsub_rn(q.w, q.y));
    smax[t] = 0ull;
  }
  __syncthreads();

  float4 p = bbox[img * A_N + a];
  float pa = __fmul_rn(__fsub_rn(p.z, p.x), __fsub_rn(p.w, p.y));

  float biou = -1.0f;
  int bidx = 0;
  const unsigned long long keylo = (unsigned long long)(~(uint32_t)a);  // smaller idx wins ties under max

  for (int g = 0; g < G_N; ++g) {
    float4 q = sg[g];
    float ix1 = fmaxf(p.x, q.x), iy1 = fmaxf(p.y, q.y);
    float ix2 = fminf(p.z, q.z), iy2 = fminf(p.w, q.w);
    float iw = fmaxf(__fsub_rn(ix2, ix1), 0.0f);
    float ih = fmaxf(__fsub_rn(iy2, iy1), 0.0f);
    float inter = __fmul_rn(iw, ih);
    // ((area_a + area_b) - inter) + EPS  — same association as reference
    float den = __fadd_rn(__fsub_rn(__fadd_rn(pa, sga[g]), inter), FEPS);
    float iou = __fdiv_rn(inter, den);  // IEEE-exact quotient

    if (iou > biou) { biou = iou; bidx = g; }  // strict > keeps first occurrence

    if (iou > 0.0f) {
      unsigned long long key = ((unsigned long long)__float_as_uint(iou) << 32) | keylo;
      // monotonic filter: stale reads are safe (any historical value <= current max)
      if (key > smax[g]) atomicMax(&smax[g], key);
    }
  }

  best_iou[img * A_N + a] = biou;
  best_idx[img * A_N + a] = (uint32_t)bidx;

  __syncthreads();
  if (t < G_N && smax[t] != 0ull) atomicMax(&gt_key[img * G_N + t], smax[t]);
}

// ---------------- K2: force best anchor per GT positive ----------------
__global__ void dl_force(const unsigned long long* __restrict__ gt_key,
                         float* __restrict__ best_iou) {
  int i = blockIdx.x * blockDim.x + threadIdx.x;
  if (i < B_N * G_N) {
    int img = i >> 6;
    uint32_t a = ~(uint32_t)(gt_key[i] & 0xFFFFFFFFull);
    best_iou[img * A_N + a] = 2.0f;  // > 0.5 => positive; best_idx untouched (matched gt unchanged)
  }
}

// ---------------- K3: focal loss, DIoU for positives, per-image accumulators, neg keys ----------------
__global__ __launch_bounds__(256) void dl_pass2(
    const float4* __restrict__ bbox, const float* __restrict__ conf,
    const float4* __restrict__ gt,
    const float* __restrict__ best_iou, const uint32_t* __restrict__ best_idx,
    uint32_t* __restrict__ negkey, float* __restrict__ acc) {
  const int img = blockIdx.y;
  const int a = blockIdx.x * 256 + threadIdx.x;
  const int idx = img * A_N + a;

  const float biou = best_iou[idx];
  const bool pos = biou > 0.5f;

  const float l = conf[idx];
  const float tt = pos ? 1.0f : 0.0f;
  float ce = fmaxf(l, 0.0f) - l * tt + log1pf(expf(-fabsf(l)));
  float pp = 1.0f / (1.0f + expf(-l));
  float pt = pp * tt + (1.0f - pp) * (1.0f - tt);
  pt = fminf(fmaxf(pt, FEPS), 1.0f - FEPS);
  float om = 1.0f - pt;
  float fl = (pos ? 0.25f : 0.75f) * om * om * ce;

  negkey[idx] = pos ? 0u : __float_as_uint(fl);  // fl > 0 strictly, so 0 sentinel sorts below all negatives

  float locv = 0.0f;
  if (pos) {
    float4 p = bbox[idx];
    float4 q = gt[img * G_N + best_idx[idx]];
    float ap = (p.z - p.x) * (p.w - p.y);
    float ag = (q.z - q.x) * (q.w - q.y);
    float ix1 = fmaxf(p.x, q.x), iy1 = fmaxf(p.y, q.y);
    float ix2 = fminf(p.z, q.z), iy2 = fminf(p.w, q.w);
    float iw = fmaxf(ix2 - ix1, 0.0f), ih = fmaxf(iy2 - iy1, 0.0f);
    float inter = iw * ih;
    float iou = inter / (ap + ag - inter + FEPS);
    float cpx = (p.x + p.z) * 0.5f, cpy = (p.y + p.w) * 0.5f;
    float cgx = (q.x + q.z) * 0.5f, cgy = (q.y + q.w) * 0.5f;
    float dx = cpx - cgx, dy = cpy - cgy;
    float cd2 = dx * dx + dy * dy;
    float ex1 = fminf(p.x, q.x), ey1 = fminf(p.y, q.y);
    float ex2 = fmaxf(p.z, q.z), ey2 = fmaxf(p.w, q.w);
    float ddx = ex2 - ex1, ddy = ey2 - ey1;
    float dg2 = ddx * ddx + ddy * ddy + FEPS;
    locv = 1.0f - iou + cd2 / dg2;  // LOC_LOSS_WEIGHT = 1
  }

  float flp = pos ? fl : 0.0f;
  float np1 = pos ? 1.0f : 0.0f;
  for (int o = 32; o; o >>= 1) {
    locv += __shfl_down(locv, o);
    flp  += __shfl_down(flp, o);
    np1  += __shfl_down(np1, o);
  }
  if ((threadIdx.x & 63) == 0) {
    atomicAdd(&acc[img], locv);
    atomicAdd(&acc[16 + img], flp);
    atomicAdd(&acc[32 + img], np1);  // integer-valued floats, exact below 2^24
  }
}

// ---------------- K4: per-image exact top-k negative sum via bisection on uint keys ----------------
__global__ __launch_bounds__(1024) void dl_select(
    const uint32_t* __restrict__ negkey, float* __restrict__ acc) {
  const int img = blockIdx.x;
  const int t = threadIdx.x;
  const uint4* __restrict__ k4 = (const uint4*)(negkey + img * A_N);
  const int N4 = A_N / 4;  // 16384

  __shared__ float sredf[16];
  __shared__ int   sredi[16];

  const int np = (int)(acc[32 + img] + 0.5f);
  const int k = min(A_N - np, 3 * np);

  float neg_sum = 0.0f;
  if (k > 0) {
    uint32_t lo = 0u, hi = 0x7F800000u;  // invariant: count(>=lo) >= k > count(>=hi)
    while (hi - lo > 1u) {
      uint32_t mid = lo + ((hi - lo) >> 1);
      int c = 0;
      for (int i = t; i < N4; i += 1024) {
        uint4 v = k4[i];
        c += (v.x >= mid) + (v.y >= mid) + (v.z >= mid) + (v.w >= mid);
      }
      for (int o = 32; o; o >>= 1) c += __shfl_down(c, o);
      if ((t & 63) == 0) sredi[t >> 6] = c;
      __syncthreads();
      c = 0;
      #pragma unroll
      for (int w = 0; w < 16; ++w) c += sredi[w];
      __syncthreads();
      if (c >= k) lo = mid; else hi = mid;  // uniform across block
    }
    // lo == k-th largest key value
    float s = 0.0f;
    int cg = 0;
    for (int i = t; i < N4; i += 1024) {
      uint4 v = k4[i];
      if (v.x > lo) { s += __uint_as_float(v.x); cg++; }
      if (v.y > lo) { s += __uint_as_float(v.y); cg++; }
      if (v.z > lo) { s += __uint_as_float(v.z); cg++; }
      if (v.w > lo) { s += __uint_as_float(v.w); cg++; }
    }
    for (int o = 32; o; o >>= 1) { s += __shfl_down(s, o); cg += __shfl_down(cg, o); }
    if ((t & 63) == 0) { sredf[t >> 6] = s; sredi[t >> 6] = cg; }
    __syncthreads();
    if (t == 0) {
      float ss = 0.0f; int cc = 0;
      #pragma unroll
      for (int w = 0; w < 16; ++w) { ss += sredf[w]; cc += sredi[w]; }
      neg_sum = ss + (float)(k - cc) * __uint_as_float(lo);
    }
  }
  if (t == 0) {
    float psum = acc[16 + img];
    acc[48 + img] = (psum + neg_sum) / fmaxf((float)(np + k), 1.0f);
  }
}

// ---------------- K5: final combine ----------------
__global__ void dl_final(const float* __restrict__ acc, float* __restrict__ out) {
  if (threadIdx.x == 0 && blockIdx.x == 0) {
    float sl = 0.0f, sc = 0.0f, sn = 0.0f;
    for (int i = 0; i < B_N; ++i) {
      sl += acc[i];
      sc += acc[48 + i];
      sn += acc[32 + i];
    }
    float tp = fmaxf(sn, 1.0f);
    float al = sl / tp;
    float ac = sc / tp;
    out[0] = al + ac;
    out[1] = ac;
    out[2] = al;
  }
}

extern "C" void kernel_launch(void* const* d_in, const int* in_sizes, int n_in,
                              void* d_out, int out_size, void* d_ws, size_t ws_size,
                              hipStream_t stream) {
  (void)in_sizes; (void)n_in; (void)out_size; (void)ws_size;

  const float4* bbox = (const float4*)d_in[0];   // [B, A, 4] f32
  const float*  conf = (const float*)d_in[1];    // [B, A] f32
  const float4* gt   = (const float4*)d_in[2];   // [B, G, 4] f32
  float* out = (float*)d_out;

  char* ws = (char*)d_ws;
  const size_t SZ = (size_t)B_N * A_N * 4;       // 4 MiB per array
  float*              best_iou = (float*)(ws);
  uint32_t*           best_idx = (uint32_t*)(ws + SZ);
  uint32_t*           negkey   = (uint32_t*)(ws + 2 * SZ);
  unsigned long long* gt_key   = (unsigned long long*)(ws + 3 * SZ);
  float*              acc      = (float*)(ws + 3 * SZ + (size_t)B_N * G_N * 8);

  dl_init<<<1, 1024, 0, stream>>>(gt_key, acc);
  dl_pass1<<<dim3(A_N / 256, B_N), 256, 0, stream>>>(bbox, gt, best_iou, best_idx, gt_key);
  dl_force<<<1, 1024, 0, stream>>>(gt_key, best_iou);
  dl_pass2<<<dim3(A_N / 256, B_N), 256, 0, stream>>>(bbox, conf, gt, best_iou, best_idx, negkey, acc);
  dl_select<<<B_N, 1024, 0, stream>>>(negkey, acc);
  dl_final<<<1, 64, 0, stream>>>(acc, out);
}

// Round 2
// 234.137 us; speedup vs baseline: 2.2520x; 2.2520x over previous
//
#include <hip/hip_runtime.h>
#include <stdint.h>

#define A_N 65536
#define B_N 16
#define G_N 64
#define FEPS 1e-7f

// ---------------- K1: per-anchor best gt (max+argmax), per-(block,gt) best-anchor key ----------------
__global__ __launch_bounds__(256) void dl_pass1(
    const float4* __restrict__ bbox, const float4* __restrict__ gt,
    float* __restrict__ best_iou, uint8_t* __restrict__ best_idx,
    unsigned long long* __restrict__ gt_part) {
  const int img = blockIdx.y;
  const int bx = blockIdx.x;
  const int a = bx * 256 + threadIdx.x;
  const int t = threadIdx.x;

  __shared__ float4 sg[G_N];
  __shared__ float sga[G_N];
  __shared__ unsigned long long smax[G_N];

  if (t < G_N) {
    float4 q = gt[img * G_N + t];
    sg[t] = q;
    // exact f32, no contraction (matches numpy bit-for-bit)
    sga[t] = __fmul_rn(__fsub_rn(q.z, q.x), __fsub_rn(q.w, q.y));
    smax[t] = 0ull;
  }
  __syncthreads();

  float4 p = bbox[img * A_N + a];
  float pa = __fmul_rn(__fsub_rn(p.z, p.x), __fsub_rn(p.w, p.y));

  float biou = -1.0f;
  int bidx = 0;
  const unsigned long long keylo = (unsigned long long)(~(uint32_t)a);  // smaller idx wins ties under max

  for (int g = 0; g < G_N; ++g) {
    float4 q = sg[g];
    float ix1 = fmaxf(p.x, q.x), iy1 = fmaxf(p.y, q.y);
    float ix2 = fminf(p.z, q.z), iy2 = fminf(p.w, q.w);
    float iw = fmaxf(__fsub_rn(ix2, ix1), 0.0f);
    float ih = fmaxf(__fsub_rn(iy2, iy1), 0.0f);
    float inter = __fmul_rn(iw, ih);
    // ((area_a + area_b) - inter) + EPS  — same association as reference
    float den = __fadd_rn(__fsub_rn(__fadd_rn(pa, sga[g]), inter), FEPS);
    float iou = __fdiv_rn(inter, den);  // IEEE-exact quotient

    if (iou > biou) { biou = iou; bidx = g; }  // strict > keeps first occurrence

    if (iou > 0.0f) {
      unsigned long long key = ((unsigned long long)__float_as_uint(iou) << 32) | keylo;
      // monotonic filter: stale reads are safe (any historical value <= current max)
      if (key > smax[g]) atomicMax(&smax[g], key);  // LDS atomic, block-local
    }
  }

  best_iou[img * A_N + a] = biou;
  best_idx[img * A_N + a] = (uint8_t)bidx;

  __syncthreads();
  // per-block partial: coalesced 512B store, NO global atomics
  if (t < G_N) gt_part[(((size_t)(img << 8) | bx) << 6) | t] = smax[t];
}

// ---------------- K2: reduce per-block gt keys, force best anchor per GT positive ----------------
__global__ __launch_bounds__(64) void dl_force(const unsigned long long* __restrict__ gt_part,
                                               float* __restrict__ best_iou) {
  const int p = blockIdx.x;          // 0..1023 = (img, g)
  const int img = p >> 6, g = p & 63;
  const int t = threadIdx.x;
  unsigned long long m = 0ull;
  #pragma unroll
  for (int j = 0; j < 4; ++j) {
    unsigned long long v = gt_part[(((size_t)(img << 8) | (t + j * 64)) << 6) | g];
    if (v > m) m = v;
  }
  for (int o = 32; o; o >>= 1) {
    unsigned long long other = __shfl_down(m, o);
    if (other > m) m = other;
  }
  if (t == 0) {
    // m==0 => gt had zero IoU with every anchor; numpy argmax of all-zero column = 0
    uint32_t a = (m == 0ull) ? 0u : ~(uint32_t)(m & 0xFFFFFFFFull);
    best_iou[(size_t)img * A_N + a] = 2.0f;  // > 0.5 => positive; best_idx untouched
  }
}

// ---------------- K3: focal loss, DIoU for positives, per-BLOCK partials (no atomics) ----------------
__global__ __launch_bounds__(256) void dl_pass2(
    const float4* __restrict__ bbox, const float* __restrict__ conf,
    const float4* __restrict__ gt,
    const float* __restrict__ best_iou, const uint8_t* __restrict__ best_idx,
    uint32_t* __restrict__ negkey,
    float* __restrict__ part_loc, float* __restrict__ part_fl, float* __restrict__ part_np) {
  const int img = blockIdx.y;
  const int bx = blockIdx.x;
  const int a = bx * 256 + threadIdx.x;
  const int idx = img * A_N + a;

  const float biou = best_iou[idx];
  const bool pos = biou > 0.5f;

  const float l = conf[idx];
  const float tt = pos ? 1.0f : 0.0f;
  float ce = fmaxf(l, 0.0f) - l * tt + log1pf(expf(-fabsf(l)));
  float pp = 1.0f / (1.0f + expf(-l));
  float pt = pp * tt + (1.0f - pp) * (1.0f - tt);
  pt = fminf(fmaxf(pt, FEPS), 1.0f - FEPS);
  float om = 1.0f - pt;
  float fl = (pos ? 0.25f : 0.75f) * om * om * ce;

  negkey[idx] = pos ? 0u : __float_as_uint(fl);  // fl > 0 strictly; 0 sentinel sorts below all negatives

  float locv = 0.0f;
  if (pos) {
    float4 p = bbox[idx];
    float4 q = gt[img * G_N + best_idx[idx]];
    float ap = (p.z - p.x) * (p.w - p.y);
    float ag = (q.z - q.x) * (q.w - q.y);
    float ix1 = fmaxf(p.x, q.x), iy1 = fmaxf(p.y, q.y);
    float ix2 = fminf(p.z, q.z), iy2 = fminf(p.w, q.w);
    float iw = fmaxf(ix2 - ix1, 0.0f), ih = fmaxf(iy2 - iy1, 0.0f);
    float inter = iw * ih;
    float iou = inter / (ap + ag - inter + FEPS);
    float cpx = (p.x + p.z) * 0.5f, cpy = (p.y + p.w) * 0.5f;
    float cgx = (q.x + q.z) * 0.5f, cgy = (q.y + q.w) * 0.5f;
    float dx = cpx - cgx, dy = cpy - cgy;
    float cd2 = dx * dx + dy * dy;
    float ex1 = fminf(p.x, q.x), ey1 = fminf(p.y, q.y);
    float ex2 = fmaxf(p.z, q.z), ey2 = fmaxf(p.w, q.w);
    float ddx = ex2 - ex1, ddy = ey2 - ey1;
    float dg2 = ddx * ddx + ddy * ddy + FEPS;
    locv = 1.0f - iou + cd2 / dg2;  // LOC_LOSS_WEIGHT = 1
  }

  float flp = pos ? fl : 0.0f;
  float np1 = pos ? 1.0f : 0.0f;
  for (int o = 32; o; o >>= 1) {
    locv += __shfl_down(locv, o);
    flp  += __shfl_down(flp, o);
    np1  += __shfl_down(np1, o);
  }
  __shared__ float sl[4], sf[4], sn[4];
  if ((threadIdx.x & 63) == 0) {
    int w = threadIdx.x >> 6;
    sl[w] = locv; sf[w] = flp; sn[w] = np1;
  }
  __syncthreads();
  if (threadIdx.x == 0) {
    const int pi = img * 256 + bx;
    part_loc[pi] = sl[0] + sl[1] + sl[2] + sl[3];
    part_fl[pi]  = sf[0] + sf[1] + sf[2] + sf[3];
    part_np[pi]  = sn[0] + sn[1] + sn[2] + sn[3];  // integer-valued, exact
  }
}

// ---------------- K4: reduce partials + exact top-k negative sum via bisection ----------------
__global__ __launch_bounds__(1024) void dl_select(
    const uint32_t* __restrict__ negkey,
    const float* __restrict__ part_loc, const float* __restrict__ part_fl,
    const float* __restrict__ part_np, float* __restrict__ acc) {
  const int img = blockIdx.x;
  const int t = threadIdx.x;
  const uint4* __restrict__ k4 = (const uint4*)(negkey + (size_t)img * A_N);
  const int N4 = A_N / 4;  // 16384

  __shared__ float sredf[16];
  __shared__ int   sredi[16];
  __shared__ float s3[3][4];
  __shared__ float np_sh, psum_sh;

  // ---- prologue: reduce the 256 per-block partials of this image ----
  float lv = 0.0f, fv = 0.0f, nv = 0.0f;
  if (t < 256) {
    lv = part_loc[img * 256 + t];
    fv = part_fl[img * 256 + t];
    nv = part_np[img * 256 + t];
  }
  for (int o = 32; o; o >>= 1) {
    lv += __shfl_down(lv, o);
    fv += __shfl_down(fv, o);
    nv += __shfl_down(nv, o);
  }
  if (t < 256 && (t & 63) == 0) {
    s3[0][t >> 6] = lv; s3[1][t >> 6] = fv; s3[2][t >> 6] = nv;
  }
  __syncthreads();
  if (t == 0) {
    float L = s3[0][0] + s3[0][1] + s3[0][2] + s3[0][3];
    float F = s3[1][0] + s3[1][1] + s3[1][2] + s3[1][3];
    float N = s3[2][0] + s3[2][1] + s3[2][2] + s3[2][3];
    acc[img] = L;          // loc sum for this image
    psum_sh = F;
    np_sh = N;
  }
  __syncthreads();

  const int np = (int)(np_sh + 0.5f);
  const int k = min(A_N - np, 3 * np);

  float neg_sum = 0.0f;
  if (k > 0) {
    uint32_t lo = 0u, hi = 0x7F800000u;  // invariant: count(>=lo) >= k > count(>=hi)
    while (hi - lo > 1u) {
      uint32_t mid = lo + ((hi - lo) >> 1);
      int c = 0;
      for (int i = t; i < N4; i += 1024) {
        uint4 v = k4[i];
        c += (v.x >= mid) + (v.y >= mid) + (v.z >= mid) + (v.w >= mid);
      }
      for (int o = 32; o; o >>= 1) c += __shfl_down(c, o);
      if ((t & 63) == 0) sredi[t >> 6] = c;
      __syncthreads();
      c = 0;
      #pragma unroll
      for (int w = 0; w < 16; ++w) c += sredi[w];
      __syncthreads();
      if (c >= k) lo = mid; else hi = mid;  // uniform across block
    }
    // lo == k-th largest key value
    float s = 0.0f;
    int cg = 0;
    for (int i = t; i < N4; i += 1024) {
      uint4 v = k4[i];
      if (v.x > lo) { s += __uint_as_float(v.x); cg++; }
      if (v.y > lo) { s += __uint_as_float(v.y); cg++; }
      if (v.z > lo) { s += __uint_as_float(v.z); cg++; }
      if (v.w > lo) { s += __uint_as_float(v.w); cg++; }
    }
    for (int o = 32; o; o >>= 1) { s += __shfl_down(s, o); cg += __shfl_down(cg, o); }
    if ((t & 63) == 0) { sredf[t >> 6] = s; sredi[t >> 6] = cg; }
    __syncthreads();
    if (t == 0) {
      float ss = 0.0f; int cc = 0;
      #pragma unroll
      for (int w = 0; w < 16; ++w) { ss += sredf[w]; cc += sredi[w]; }
      neg_sum = ss + (float)(k - cc) * __uint_as_float(lo);
    }
  }
  if (t == 0) {
    acc[32 + img] = (float)np;
    acc[48 + img] = (psum_sh + neg_sum) / fmaxf((float)(np + k), 1.0f);
  }
}

// ---------------- K5: final combine ----------------
__global__ void dl_final(const float* __restrict__ acc, float* __restrict__ out) {
  if (threadIdx.x == 0 && blockIdx.x == 0) {
    float sl = 0.0f, sc = 0.0f, sn = 0.0f;
    for (int i = 0; i < B_N; ++i) {
      sl += acc[i];
      sc += acc[48 + i];
      sn += acc[32 + i];
    }
    float tp = fmaxf(sn, 1.0f);
    float al = sl / tp;
    float ac = sc / tp;
    out[0] = al + ac;
    out[1] = ac;
    out[2] = al;
  }
}

extern "C" void kernel_launch(void* const* d_in, const int* in_sizes, int n_in,
                              void* d_out, int out_size, void* d_ws, size_t ws_size,
                              hipStream_t stream) {
  (void)in_sizes; (void)n_in; (void)out_size; (void)ws_size;

  const float4* bbox = (const float4*)d_in[0];   // [B, A, 4] f32
  const float*  conf = (const float*)d_in[1];    // [B, A] f32
  const float4* gt   = (const float4*)d_in[2];   // [B, G, 4] f32
  float* out = (float*)d_out;

  char* ws = (char*)d_ws;
  const size_t SZ = (size_t)B_N * A_N * 4;                 // 4 MiB
  float*              best_iou = (float*)(ws);             // 4 MiB
  uint32_t*           negkey   = (uint32_t*)(ws + SZ);     // 4 MiB
  unsigned long long* gt_part  = (unsigned long long*)(ws + 2 * SZ);          // 2 MiB [16][256][64]
  uint8_t*            best_idx = (uint8_t*)(ws + 2 * SZ + (size_t)B_N * 256 * G_N * 8);  // 1 MiB
  char* tail = ws + 2 * SZ + (size_t)B_N * 256 * G_N * 8 + (size_t)B_N * A_N;
  float* part_loc = (float*)(tail);                        // 16 KiB
  float* part_fl  = (float*)(tail + 16384);
  float* part_np  = (float*)(tail + 32768);
  float* acc      = (float*)(tail + 49152);                // 64 floats

  dl_pass1<<<dim3(A_N / 256, B_N), 256, 0, stream>>>(bbox, gt, best_iou, best_idx, gt_part);
  dl_force<<<B_N * G_N, 64, 0, stream>>>(gt_part, best_iou);
  dl_pass2<<<dim3(A_N / 256, B_N), 256, 0, stream>>>(bbox, conf, gt, best_iou, best_idx,
                                                     negkey, part_loc, part_fl, part_np);
  dl_select<<<B_N, 1024, 0, stream>>>(negkey, part_loc, part_fl, part_np, acc);
  dl_final<<<1, 64, 0, stream>>>(acc, out);
}